// Round 3
// baseline (225.473 us; speedup 1.0000x reference)
//
#include <hip/hip_runtime.h>

typedef _Float16 f16;
typedef _Float16 f16x2 __attribute__((ext_vector_type(2)));
typedef _Float16 f16x8 __attribute__((ext_vector_type(8)));
typedef float    f32x4 __attribute__((ext_vector_type(4)));

#define DIM 128

// silu(x) = x / (1 + e^-x); v_exp_f32 computes 2^x -> scale by log2(e).
__device__ __forceinline__ float silu_f(float x) {
    float e = __builtin_amdgcn_exp2f(x * -1.44269504088896341f);
    return x * __builtin_amdgcn_rcpf(1.0f + e);
}

// Block = 256 threads = 4 waves; ONE 64-row tile per block (grid = B/64).
// Wave wv owns output cols [32wv,32wv+32): W1/W2 frags in registers (64 VGPR).
// LDS (32KB union):
//   phase A: embf (16KB, A-frag exchange) + x1s (16KB, xor-swizzled fp16)
//   phase B: ostage (32KB fp32, chunk-xor swizzled) for full-line stores.
__global__ __launch_bounds__(256, 4)
void ts_mlp_kernel(const float* __restrict__ t,
                   const float* __restrict__ W1, const float* __restrict__ b1,
                   const float* __restrict__ W2, const float* __restrict__ b2,
                   float* __restrict__ out, int B) {
    __shared__ union SH {
        struct { f16x8 embf[4][4][64]; f16x2 x1s[1024][4]; } p;
        float ostage[64 * 128];
    } sh;

    const int tid  = threadIdx.x;
    const int wv   = tid >> 6;
    const int lane = tid & 63;
    const int q    = lane >> 4;   // quad 0..3
    const int ln   = lane & 15;
    const int par  = lane & 1;

    const int row0 = blockIdx.x * 64;

    // ---- t for this wave's 16 rows (64B segment, broadcast across quads)
    const float tv = t[row0 + wv * 16 + ln];

    // ---- weights -> registers, mfma_f32_16x16x32_f16 B-frag layout.
    // Frag (kt,u): B[k][n], n = 32wv+16u+ln, k = 32kt+8q+j  (= W[n][k])
    f16x8 w1f[4][2], w2f[4][2];
    float b1v[2], b2v[2];
#pragma unroll
    for (int u = 0; u < 2; ++u) {
        const int n = wv * 32 + u * 16 + ln;
        b1v[u] = b1[n];
        b2v[u] = b2[n];
#pragma unroll
        for (int kt = 0; kt < 4; ++kt) {
            const float4* p1 = (const float4*)(W1 + n * DIM + kt * 32 + q * 8);
            const float4* p2 = (const float4*)(W2 + n * DIM + kt * 32 + q * 8);
            const float4 a = p1[0], b = p1[1], c = p2[0], d = p2[1];
            f16x8 f1, f2;
            f1[0]=(f16)a.x; f1[1]=(f16)a.y; f1[2]=(f16)a.z; f1[3]=(f16)a.w;
            f1[4]=(f16)b.x; f1[5]=(f16)b.y; f1[6]=(f16)b.z; f1[7]=(f16)b.w;
            f2[0]=(f16)c.x; f2[1]=(f16)c.y; f2[2]=(f16)c.z; f2[3]=(f16)c.w;
            f2[4]=(f16)d.x; f2[5]=(f16)d.y; f2[6]=(f16)d.z; f2[7]=(f16)d.w;
            w1f[kt][u] = f1;
            w2f[kt][u] = f2;
        }
    }

    // ---- emb for this wave's 16 rows, directly in A-frag layout:
    // row m = ln, k = 32kt+8q+j. v_sin/v_cos take REVOLUTIONS: rev = d*t/256.
    {
        const float t256 = tv * 0.00390625f;
        const float o256 = (1.0f - tv) * 0.00390625f;
        const float qb   = (float)(q * 8);
#pragma unroll
        for (int kt = 0; kt < 4; ++kt) {
            f16x8 ef;
#pragma unroll
            for (int j = 0; j < 8; ++j) {
                const float fd = (float)(kt * 32 + j) + qb;
                const float c  = __builtin_amdgcn_cosf(fd * t256);
                const float s  = __builtin_amdgcn_sinf(fd * o256);
                ef[j] = (f16)(tv * (c + s));
            }
            sh.p.embf[wv][kt][lane] = ef;   // b128, conflict-free
        }
    }
    __syncthreads();   // b1: embf ready

    // ---- layer 1: 32 MFMAs (W1 in regs)
    f32x4 acc[4][2];
#pragma unroll
    for (int mt = 0; mt < 4; ++mt) {
        acc[mt][0] = (f32x4){0.f,0.f,0.f,0.f};
        acc[mt][1] = (f32x4){0.f,0.f,0.f,0.f};
#pragma unroll
        for (int kt = 0; kt < 4; ++kt) {
            const f16x8 af = sh.p.embf[mt][kt][lane];
            acc[mt][0] = __builtin_amdgcn_mfma_f32_16x16x32_f16(af, w1f[kt][0], acc[mt][0], 0, 0, 0);
            acc[mt][1] = __builtin_amdgcn_mfma_f32_16x16x32_f16(af, w1f[kt][1], acc[mt][1], 0, 0, 0);
        }
    }

    // ---- epilogue 1: bias+silu, pair-pack cross-lane, fp16 x1 -> LDS (swizzled).
    // C layout: value r in lane = x1[row = mt*16+q*4+r][col = 32wv+16u+ln]
#pragma unroll
    for (int mt = 0; mt < 4; ++mt) {
#pragma unroll
        for (int u = 0; u < 2; ++u) {
            float v[4], pv[4];
#pragma unroll
            for (int r = 0; r < 4; ++r) v[r] = silu_f(acc[mt][u][r] + b1v[u]);
#pragma unroll
            for (int r = 0; r < 4; ++r) pv[r] = __shfl_xor(v[r], 1, 64);
            const int k0  = wv * 32 + u * 16 + (ln & 14); // even col of pair
            const int cch = k0 >> 3;                       // 16B chunk 0..15
            const int hw  = (k0 & 7) >> 1;                 // dword in chunk
#pragma unroll
            for (int p = 0; p < 2; ++p) {
                const int r = par * 2 + p;   // even lanes rows 0,1; odd rows 2,3
                const int m = mt * 16 + q * 4 + r;
                const float lo = par ? pv[r] : v[r];
                const float hi = par ? v[r] : pv[r];
                f16x2 h; h.x = (f16)lo; h.y = (f16)hi;
                sh.p.x1s[m * 16 + (cch ^ (m & 15))][hw] = h;
            }
        }
    }
    __syncthreads();   // b2: x1s ready

    // ---- layer 2: A-frags from x1s, 32 MFMAs (W2 in regs)
    f32x4 acc2[4][2];
#pragma unroll
    for (int mt = 0; mt < 4; ++mt) {
        acc2[mt][0] = (f32x4){0.f,0.f,0.f,0.f};
        acc2[mt][1] = (f32x4){0.f,0.f,0.f,0.f};
    }
#pragma unroll
    for (int kt = 0; kt < 4; ++kt) {
#pragma unroll
        for (int mt = 0; mt < 4; ++mt) {
            const int m = mt * 16 + ln;
            const f16x8 a2 = *(const f16x8*)&sh.p.x1s[m * 16 + ((kt * 4 + q) ^ ln)][0];
            acc2[mt][0] = __builtin_amdgcn_mfma_f32_16x16x32_f16(a2, w2f[kt][0], acc2[mt][0], 0, 0, 0);
            acc2[mt][1] = __builtin_amdgcn_mfma_f32_16x16x32_f16(a2, w2f[kt][1], acc2[mt][1], 0, 0, 0);
        }
    }
    __syncthreads();   // b3: x1s/embf fully consumed by ALL waves

    // ---- epilogue 2: bias+silu -> fp32 ostage (chunk-xor swizzle, 2-way max).
    // logical (m, col) -> phys word m*128 + (((col>>2) ^ (m&7))<<2) + (col&3)
#pragma unroll
    for (int mt = 0; mt < 4; ++mt) {
#pragma unroll
        for (int u = 0; u < 2; ++u) {
            const int cc = wv * 8 + u * 4 + (ln >> 2);   // logical chunk
            const int w  = ln & 3;
#pragma unroll
            for (int r = 0; r < 4; ++r) {
                const int m = mt * 16 + q * 4 + r;
                const float o = silu_f(acc2[mt][u][r] + b2v[u]);
                sh.ostage[m * 128 + ((cc ^ (m & 7)) << 2) + w] = o;
            }
        }
    }
    __syncthreads();   // b4: ostage ready

    // ---- coalesced stores: each wave writes 2 full 512B rows per iteration
#pragma unroll
    for (int it = 0; it < 8; ++it) {
        const int m = it * 8 + (tid >> 5);
        const int c = tid & 31;
        const float4 v = *(const float4*)&sh.ostage[m * 128 + ((c ^ (m & 7)) << 2)];
        *(float4*)(out + (size_t)(row0 + m) * DIM + 4 * c) = v;
    }
}

extern "C" void kernel_launch(void* const* d_in, const int* in_sizes, int n_in,
                              void* d_out, int out_size, void* d_ws, size_t ws_size,
                              hipStream_t stream) {
    const float* t  = (const float*)d_in[0];
    const float* W1 = (const float*)d_in[1];
    const float* b1 = (const float*)d_in[2];
    const float* W2 = (const float*)d_in[3];
    const float* b2 = (const float*)d_in[4];
    float* out = (float*)d_out;
    const int B = in_sizes[0];
    const int grid = B >> 6;   // one 64-row tile per block
    ts_mlp_kernel<<<dim3(grid), dim3(256), 0, stream>>>(t, W1, b1, W2, b2, out, B);
}

// Round 4
// 198.145 us; speedup vs baseline: 1.1379x; 1.1379x over previous
//
#include <hip/hip_runtime.h>

typedef _Float16 f16;
typedef _Float16 f16x2 __attribute__((ext_vector_type(2)));
typedef _Float16 f16x8 __attribute__((ext_vector_type(8)));
typedef float    f32x4 __attribute__((ext_vector_type(4)));

#define DIM 128

// silu(x) = x / (1 + e^-x); v_exp_f32 computes 2^x -> scale by log2(e).
__device__ __forceinline__ float silu_f(float x) {
    float e = __builtin_amdgcn_exp2f(x * -1.44269504088896341f);
    return x * __builtin_amdgcn_rcpf(1.0f + e);
}

// ---- K1: one-time weight repack. W1,W2 (fp32, row-major [n][k]) ->
// f16x8 B-frags in ws, indexed [wv][mtx][kt][u][lane] flat; gid == frag index.
// This kernel eats the 64-lines-per-instr gather ONCE (16 blocks) instead of
// per main-kernel block (4096x).
__global__ __launch_bounds__(256)
void prep_weights(const float* __restrict__ W1, const float* __restrict__ W2,
                  f16x8* __restrict__ ws) {
    const int gid  = blockIdx.x * 256 + threadIdx.x;   // 0..4095
    const int lane = gid & 63;
    const int rest = gid >> 6;          // (((wv*2+mtx)*4+kt)*2+u)
    const int u    = rest & 1;
    const int kt   = (rest >> 1) & 3;
    const int mtx  = (rest >> 3) & 1;
    const int wv   = rest >> 4;
    const float* W = mtx ? W2 : W1;
    const int q  = lane >> 4;
    const int ln = lane & 15;
    const int n  = wv * 32 + u * 16 + ln;               // output col
    const float4* p = (const float4*)(W + n * DIM + kt * 32 + q * 8);
    const float4 a = p[0], b = p[1];
    f16x8 f;
    f[0]=(f16)a.x; f[1]=(f16)a.y; f[2]=(f16)a.z; f[3]=(f16)a.w;
    f[4]=(f16)b.x; f[5]=(f16)b.y; f[6]=(f16)b.z; f[7]=(f16)b.w;
    ws[gid] = f;   // consecutive threads -> consecutive 16B: coalesced
}

// ---- K2: block = 256 threads = 4 waves; ONE 64-row tile per block.
// Wave wv owns output cols [32wv,32wv+32): W1/W2 frags in registers, loaded
// COALESCED from ws (lane-consecutive 16B). LDS (32KB union):
//   phase A: embf (16KB, A-frag exchange) + x1s (16KB, xor-swizzled fp16)
//   phase B: ostage (32KB fp32, chunk-xor swizzled) for full-line stores.
__global__ __launch_bounds__(256, 5)
void ts_mlp_kernel(const float* __restrict__ t,
                   const f16x8* __restrict__ wsf,
                   const float* __restrict__ b1, const float* __restrict__ b2,
                   float* __restrict__ out, int B) {
    __shared__ union SH {
        struct { f16x8 embf[4][4][64]; f16x2 x1s[1024][4]; } p;
        float ostage[64 * 128];
    } sh;

    const int tid  = threadIdx.x;
    const int wv   = tid >> 6;
    const int lane = tid & 63;
    const int q    = lane >> 4;   // quad 0..3
    const int ln   = lane & 15;
    const int par  = lane & 1;

    const int row0 = blockIdx.x * 64;

    // ---- t for this wave's 16 rows (64B segment, broadcast across quads)
    const float tv = t[row0 + wv * 16 + ln];

    // ---- weights: coalesced frag loads (consecutive lanes -> consecutive 16B)
    f16x8 w1f[4][2], w2f[4][2];
    float b1v[2], b2v[2];
#pragma unroll
    for (int u = 0; u < 2; ++u) {
        const int n = wv * 32 + u * 16 + ln;
        b1v[u] = b1[n];
        b2v[u] = b2[n];
#pragma unroll
        for (int kt = 0; kt < 4; ++kt) {
            w1f[kt][u] = wsf[(((((wv * 2 + 0) * 4 + kt) * 2) + u) << 6) + lane];
            w2f[kt][u] = wsf[(((((wv * 2 + 1) * 4 + kt) * 2) + u) << 6) + lane];
        }
    }

    // ---- emb for this wave's 16 rows, directly in A-frag layout:
    // row m = ln, k = 32kt+8q+j. v_sin/v_cos take REVOLUTIONS: rev = d*t/256.
    {
        const float t256 = tv * 0.00390625f;
        const float o256 = (1.0f - tv) * 0.00390625f;
        const float qb   = (float)(q * 8);
#pragma unroll
        for (int kt = 0; kt < 4; ++kt) {
            f16x8 ef;
#pragma unroll
            for (int j = 0; j < 8; ++j) {
                const float fd = (float)(kt * 32 + j) + qb;
                const float c  = __builtin_amdgcn_cosf(fd * t256);
                const float s  = __builtin_amdgcn_sinf(fd * o256);
                ef[j] = (f16)(tv * (c + s));
            }
            sh.p.embf[wv][kt][lane] = ef;   // b128, conflict-free
        }
    }
    __syncthreads();   // b1: embf ready

    // ---- layer 1: 32 MFMAs (W1 in regs)
    f32x4 acc[4][2];
#pragma unroll
    for (int mt = 0; mt < 4; ++mt) {
        acc[mt][0] = (f32x4){0.f,0.f,0.f,0.f};
        acc[mt][1] = (f32x4){0.f,0.f,0.f,0.f};
#pragma unroll
        for (int kt = 0; kt < 4; ++kt) {
            const f16x8 af = sh.p.embf[mt][kt][lane];
            acc[mt][0] = __builtin_amdgcn_mfma_f32_16x16x32_f16(af, w1f[kt][0], acc[mt][0], 0, 0, 0);
            acc[mt][1] = __builtin_amdgcn_mfma_f32_16x16x32_f16(af, w1f[kt][1], acc[mt][1], 0, 0, 0);
        }
    }

    // ---- epilogue 1: bias+silu, pair-pack cross-lane, fp16 x1 -> LDS (swizzled).
    // C layout: value r in lane = x1[row = mt*16+q*4+r][col = 32wv+16u+ln]
#pragma unroll
    for (int mt = 0; mt < 4; ++mt) {
#pragma unroll
        for (int u = 0; u < 2; ++u) {
            float v[4], pv[4];
#pragma unroll
            for (int r = 0; r < 4; ++r) v[r] = silu_f(acc[mt][u][r] + b1v[u]);
#pragma unroll
            for (int r = 0; r < 4; ++r) pv[r] = __shfl_xor(v[r], 1, 64);
            const int k0  = wv * 32 + u * 16 + (ln & 14); // even col of pair
            const int cch = k0 >> 3;                       // 16B chunk 0..15
            const int hw  = (k0 & 7) >> 1;                 // dword in chunk
#pragma unroll
            for (int p = 0; p < 2; ++p) {
                const int r = par * 2 + p;   // even lanes rows 0,1; odd rows 2,3
                const int m = mt * 16 + q * 4 + r;
                const float lo = par ? pv[r] : v[r];
                const float hi = par ? v[r] : pv[r];
                f16x2 h; h.x = (f16)lo; h.y = (f16)hi;
                sh.p.x1s[m * 16 + (cch ^ (m & 15))][hw] = h;
            }
        }
    }
    __syncthreads();   // b2: x1s ready

    // ---- layer 2: A-frags from x1s, 32 MFMAs (W2 in regs)
    f32x4 acc2[4][2];
#pragma unroll
    for (int mt = 0; mt < 4; ++mt) {
        acc2[mt][0] = (f32x4){0.f,0.f,0.f,0.f};
        acc2[mt][1] = (f32x4){0.f,0.f,0.f,0.f};
    }
#pragma unroll
    for (int kt = 0; kt < 4; ++kt) {
#pragma unroll
        for (int mt = 0; mt < 4; ++mt) {
            const int m = mt * 16 + ln;
            const f16x8 a2 = *(const f16x8*)&sh.p.x1s[m * 16 + ((kt * 4 + q) ^ ln)][0];
            acc2[mt][0] = __builtin_amdgcn_mfma_f32_16x16x32_f16(a2, w2f[kt][0], acc2[mt][0], 0, 0, 0);
            acc2[mt][1] = __builtin_amdgcn_mfma_f32_16x16x32_f16(a2, w2f[kt][1], acc2[mt][1], 0, 0, 0);
        }
    }
    __syncthreads();   // b3: x1s/embf fully consumed by ALL waves

    // ---- epilogue 2: bias+silu -> fp32 ostage (chunk-xor swizzle, 2-way max).
    // logical (m, col) -> phys word m*128 + (((col>>2) ^ (m&7))<<2) + (col&3)
#pragma unroll
    for (int mt = 0; mt < 4; ++mt) {
#pragma unroll
        for (int u = 0; u < 2; ++u) {
            const int cc = wv * 8 + u * 4 + (ln >> 2);   // logical chunk
            const int w  = ln & 3;
#pragma unroll
            for (int r = 0; r < 4; ++r) {
                const int m = mt * 16 + q * 4 + r;
                const float o = silu_f(acc2[mt][u][r] + b2v[u]);
                sh.ostage[m * 128 + ((cc ^ (m & 7)) << 2) + w] = o;
            }
        }
    }
    __syncthreads();   // b4: ostage ready

    // ---- coalesced stores: each wave writes 2 full 512B rows per iteration
#pragma unroll
    for (int it = 0; it < 8; ++it) {
        const int m = it * 8 + (tid >> 5);
        const int c = tid & 31;
        const float4 v = *(const float4*)&sh.ostage[m * 128 + ((c ^ (m & 7)) << 2)];
        *(float4*)(out + (size_t)(row0 + m) * DIM + 4 * c) = v;
    }
}

extern "C" void kernel_launch(void* const* d_in, const int* in_sizes, int n_in,
                              void* d_out, int out_size, void* d_ws, size_t ws_size,
                              hipStream_t stream) {
    const float* t  = (const float*)d_in[0];
    const float* W1 = (const float*)d_in[1];
    const float* b1 = (const float*)d_in[2];
    const float* W2 = (const float*)d_in[3];
    const float* b2 = (const float*)d_in[4];
    float* out = (float*)d_out;
    const int B = in_sizes[0];

    f16x8* ws = (f16x8*)d_ws;   // needs 64 KiB
    prep_weights<<<dim3(16), dim3(256), 0, stream>>>(W1, W2, ws);

    const int grid = B >> 6;    // one 64-row tile per block
    ts_mlp_kernel<<<dim3(grid), dim3(256), 0, stream>>>(t, ws, b1, b2, out, B);
}